// Round 1
// baseline (434.169 us; speedup 1.0000x reference)
//
#include <hip/hip_runtime.h>
#include <cstdint>
#include <cstddef>

typedef __attribute__((ext_vector_type(4))) float f32x4;
typedef __attribute__((ext_vector_type(8))) short bf16x8;

#define B_    2
#define T_    2048
#define EMB_  2048
#define NQ_   32
#define NKV_  8
#define HEAD_ 64
#define NTOT_ 3072          // 2048 (Q) + 512 (K) + 512 (V)
#define M_    (B_ * T_)     // 4096

__device__ __forceinline__ unsigned short f2bf(float f) {
  union { float f; unsigned int u; } v; v.f = f;
  unsigned int r = v.u + 0x7fffu + ((v.u >> 16) & 1u);
  return (unsigned short)(r >> 16);
}

__device__ __forceinline__ void gload_lds16(const void* g, void* l) {
  __builtin_amdgcn_global_load_lds(
      (const __attribute__((address_space(1))) void*)g,
      (__attribute__((address_space(3))) void*)l, 16, 0, 0);
}

// ---------------- elementwise converts / relayouts ----------------

__global__ void cvt_bf16_kernel(const float* __restrict__ src,
                                unsigned short* __restrict__ dst, int n4) {
  int i = blockIdx.x * blockDim.x + threadIdx.x;
  if (i >= n4) return;
  float4 v = ((const float4*)src)[i];
  unsigned long long pk =
      (unsigned long long)f2bf(v.x) |
      ((unsigned long long)f2bf(v.y) << 16) |
      ((unsigned long long)f2bf(v.z) << 32) |
      ((unsigned long long)f2bf(v.w) << 48);
  *(unsigned long long*)(dst + (size_t)i * 4) = pk;
}

// src fp32 [R][C]  ->  dst bf16 [C][R]
__global__ void transpose_cvt_kernel(const float* __restrict__ src,
                                     unsigned short* __restrict__ dst,
                                     int R, int C) {
  __shared__ float tile[32][33];
  int c0 = blockIdx.x * 32, r0 = blockIdx.y * 32;
  int tx = threadIdx.x, ty = threadIdx.y;
#pragma unroll
  for (int k = 0; k < 4; ++k)
    tile[ty + 8 * k][tx] = src[(size_t)(r0 + ty + 8 * k) * C + c0 + tx];
  __syncthreads();
#pragma unroll
  for (int k = 0; k < 4; ++k)
    dst[(size_t)(c0 + ty + 8 * k) * R + r0 + tx] = f2bf(tile[tx][ty + 8 * k]);
}

__global__ void concat_bias_kernel(const float* __restrict__ bq,
                                   const float* __restrict__ bk,
                                   const float* __restrict__ bv,
                                   float* __restrict__ dst) {
  int i = blockIdx.x * 256 + threadIdx.x;
  if (i < 2048) dst[i] = bq[i];
  else if (i < 2560) dst[i] = bk[i - 2048];
  else if (i < 3072) dst[i] = bv[i - 2560];
}

#define L2_10000 13.2877123795494f

// QKVlin fp32 [4096][3072] -> Qh bf16 [b][h][t][64] with RoPE
__global__ void rope_q_kernel(const float* __restrict__ qkv,
                              unsigned short* __restrict__ Qh) {
  int idx = blockIdx.x * 256 + threadIdx.x;   // B*T*NQ*32
  int i  = idx & 31;
  int h  = (idx >> 5) & 31;
  int bt = idx >> 10;
  int t  = bt & (T_ - 1);
  int b  = bt >> 11;
  float invf = exp2f(-(float)i * (L2_10000 / 32.f));
  float ang = (float)t * invf;
  float s, c; sincosf(ang, &s, &c);
  const float* row = qkv + (size_t)bt * NTOT_ + h * 64;
  float x1 = row[i], x2 = row[i + 32];
  unsigned short* q = Qh + ((size_t)(b * NQ_ + h) * T_ + t) * HEAD_;
  q[i]      = f2bf(x1 * c - x2 * s);
  q[i + 32] = f2bf(x2 * c + x1 * s);
}

__global__ void rope_k_kernel(const float* __restrict__ qkv,
                              unsigned short* __restrict__ Kh) {
  int idx = blockIdx.x * 256 + threadIdx.x;   // B*T*NKV*32
  int i  = idx & 31;
  int kh = (idx >> 5) & 7;
  int bt = idx >> 8;
  int t  = bt & (T_ - 1);
  int b  = bt >> 11;
  float invf = exp2f(-(float)i * (L2_10000 / 32.f));
  float ang = (float)t * invf;
  float s, c; sincosf(ang, &s, &c);
  const float* row = qkv + (size_t)bt * NTOT_ + 2048 + kh * 64;
  float x1 = row[i], x2 = row[i + 32];
  unsigned short* kp = Kh + ((size_t)(b * NKV_ + kh) * T_ + t) * HEAD_;
  kp[i]      = f2bf(x1 * c - x2 * s);
  kp[i + 32] = f2bf(x2 * c + x1 * s);
}

// V -> Vt bf16 [b][kh][d][t]
__global__ void vt_kernel(const float* __restrict__ qkv,
                          unsigned short* __restrict__ Vt) {
  int idx = blockIdx.x * 256 + threadIdx.x;   // B*NKV*HEAD*T
  int t  = idx & (T_ - 1);
  int d  = (idx >> 11) & 63;
  int kh = (idx >> 17) & 7;
  int b  = idx >> 20;
  float v = qkv[(size_t)(b * T_ + t) * NTOT_ + 2560 + kh * 64 + d];
  Vt[((size_t)((b * NKV_ + kh) * 64 + d)) * T_ + t] = f2bf(v);
}

// ---------------- GEMM: C[M][N] = A[M][K](bf16) x BT[N][K](bf16) + bias ----------------
// 128x128 tile, BK=32, 4 waves (2x2), each wave 64x64 via 4x4 16x16x32 MFMA frags.

__launch_bounds__(256, 2)
__global__ void gemm_bt_bias(const unsigned short* __restrict__ A,
                             const unsigned short* __restrict__ BT,
                             const float* __restrict__ bias,
                             float* __restrict__ C, int N, int K) {
  __shared__ unsigned short Alds[128 * 32];
  __shared__ unsigned short Blds[128 * 32];
  const int tid = threadIdx.x;
  const int wave = tid >> 6, lane = tid & 63;
  const int l16 = lane & 15, lg = lane >> 4;
  const int m0 = blockIdx.x * 128;
  const int n0 = blockIdx.y * 128;
  const int wr = wave >> 1, wc = wave & 1;

  f32x4 zero4 = {0.f, 0.f, 0.f, 0.f};
  f32x4 acc[4][4];
#pragma unroll
  for (int i = 0; i < 4; ++i)
#pragma unroll
    for (int j = 0; j < 4; ++j) acc[i][j] = zero4;

  const int arow = tid >> 2;       // 0..63
  const int kcb  = (tid & 3) * 8;  // element offset within BK
  const int nk = K >> 5;
  for (int kt = 0; kt < nk; ++kt) {
    const int k0 = kt << 5;
    gload_lds16(A + (size_t)(m0 + arow) * K + k0 + kcb,       (char*)Alds + tid * 16);
    gload_lds16(A + (size_t)(m0 + 64 + arow) * K + k0 + kcb,  (char*)Alds + 4096 + tid * 16);
    gload_lds16(BT + (size_t)(n0 + arow) * K + k0 + kcb,      (char*)Blds + tid * 16);
    gload_lds16(BT + (size_t)(n0 + 64 + arow) * K + k0 + kcb, (char*)Blds + 4096 + tid * 16);
    __syncthreads();
    bf16x8 af[4], bfr[4];
#pragma unroll
    for (int i = 0; i < 4; ++i)
      af[i] = *(const bf16x8*)(Alds + (wr * 64 + i * 16 + l16) * 32 + lg * 8);
#pragma unroll
    for (int j = 0; j < 4; ++j)
      bfr[j] = *(const bf16x8*)(Blds + (wc * 64 + j * 16 + l16) * 32 + lg * 8);
#pragma unroll
    for (int i = 0; i < 4; ++i)
#pragma unroll
      for (int j = 0; j < 4; ++j)
        acc[i][j] = __builtin_amdgcn_mfma_f32_16x16x32_bf16(af[i], bfr[j], acc[i][j], 0, 0, 0);
    __syncthreads();
  }
#pragma unroll
  for (int j = 0; j < 4; ++j) {
    const int col = n0 + wc * 64 + j * 16 + l16;
    const float bv = bias[col];
#pragma unroll
    for (int i = 0; i < 4; ++i) {
      const int rowb = m0 + wr * 64 + i * 16 + lg * 4;
#pragma unroll
      for (int r = 0; r < 4; ++r)
        C[(size_t)(rowb + r) * N + col] = acc[i][j][r] + bv;
    }
  }
}

// ---------------- flash attention (causal, GQA) ----------------
// grid (T/64, NQ, B); 4 waves x 16 q-rows; KV tiles of 64.

__launch_bounds__(256, 2)
__global__ void flash_attn_kernel(const unsigned short* __restrict__ Qh,
                                  const unsigned short* __restrict__ Kh,
                                  const unsigned short* __restrict__ Vt,
                                  unsigned short* __restrict__ Y) {
  __shared__ unsigned short Klds[64 * 64];
  __shared__ unsigned short Vlds[64 * 64];
  __shared__ unsigned short Plds[4][16 * 64];
  const int tid = threadIdx.x;
  const int wave = tid >> 6, lane = tid & 63;
  const int l16 = lane & 15, lg = lane >> 4;
  const int q0 = blockIdx.x * 64;
  const int h = blockIdx.y, b = blockIdx.z;
  const int kh = h >> 2;   // N_REP = 4

  const unsigned short* qp =
      Qh + ((size_t)(b * NQ_ + h) * T_ + q0 + wave * 16 + l16) * HEAD_;
  const bf16x8 aq0 = *(const bf16x8*)(qp + lg * 8);
  const bf16x8 aq1 = *(const bf16x8*)(qp + 32 + lg * 8);

  f32x4 zero4 = {0.f, 0.f, 0.f, 0.f};
  f32x4 oacc[4];
#pragma unroll
  for (int d = 0; d < 4; ++d) oacc[d] = zero4;
  float mrow[4] = {-1e30f, -1e30f, -1e30f, -1e30f};
  float lrow[4] = {0.f, 0.f, 0.f, 0.f};

  const size_t kbase = (size_t)(b * NKV_ + kh) * T_ * HEAD_;
  const size_t vbase = (size_t)(b * NKV_ + kh) * HEAD_ * T_;
  const int qrow0 = q0 + wave * 16 + lg * 4;
  const int ntile = (q0 >> 6) + 1;

  for (int t = 0; t < ntile; ++t) {
    const int kv0 = t * 64;
    {
      const int c1 = tid + 256;
      gload_lds16(Kh + kbase + (size_t)(kv0 + (tid >> 3)) * HEAD_ + (tid & 7) * 8,
                  (char*)Klds + tid * 16);
      gload_lds16(Kh + kbase + (size_t)(kv0 + (c1 >> 3)) * HEAD_ + (c1 & 7) * 8,
                  (char*)Klds + c1 * 16);
      gload_lds16(Vt + vbase + (size_t)(tid >> 3) * T_ + kv0 + (tid & 7) * 8,
                  (char*)Vlds + tid * 16);
      gload_lds16(Vt + vbase + (size_t)(c1 >> 3) * T_ + kv0 + (c1 & 7) * 8,
                  (char*)Vlds + c1 * 16);
    }
    __syncthreads();

    // QK^T -> S[16 rows][64 kv]
    float sv[4][4];
    float pm[4] = {-1e30f, -1e30f, -1e30f, -1e30f};
#pragma unroll
    for (int cf = 0; cf < 4; ++cf) {
      const bf16x8 bk0 = *(const bf16x8*)(Klds + (cf * 16 + l16) * HEAD_ + lg * 8);
      const bf16x8 bk1 = *(const bf16x8*)(Klds + (cf * 16 + l16) * HEAD_ + 32 + lg * 8);
      f32x4 z = zero4;
      z = __builtin_amdgcn_mfma_f32_16x16x32_bf16(aq0, bk0, z, 0, 0, 0);
      z = __builtin_amdgcn_mfma_f32_16x16x32_bf16(aq1, bk1, z, 0, 0, 0);
      const int kvg = kv0 + cf * 16 + l16;
#pragma unroll
      for (int r = 0; r < 4; ++r) {
        float s = z[r] * 0.125f;
        if (kvg > qrow0 + r) s = -1e30f;
        sv[cf][r] = s;
        pm[r] = fmaxf(pm[r], s);
      }
    }
#pragma unroll
    for (int off = 8; off >= 1; off >>= 1)
#pragma unroll
      for (int r = 0; r < 4; ++r)
        pm[r] = fmaxf(pm[r], __shfl_xor(pm[r], off, 64));

    float corr[4];
#pragma unroll
    for (int r = 0; r < 4; ++r) {
      const float mnew = fmaxf(mrow[r], pm[r]);
      corr[r] = __expf(mrow[r] - mnew);
      mrow[r] = mnew;
      lrow[r] *= corr[r];
    }
#pragma unroll
    for (int df = 0; df < 4; ++df)
#pragma unroll
      for (int r = 0; r < 4; ++r) oacc[df][r] *= corr[r];

    unsigned short* pl = Plds[wave];
    float psum[4] = {0.f, 0.f, 0.f, 0.f};
#pragma unroll
    for (int cf = 0; cf < 4; ++cf)
#pragma unroll
      for (int r = 0; r < 4; ++r) {
        const float p = __expf(sv[cf][r] - mrow[r]);
        psum[r] += p;
        pl[(lg * 4 + r) * 64 + cf * 16 + l16] = f2bf(p);
      }
#pragma unroll
    for (int off = 8; off >= 1; off >>= 1)
#pragma unroll
      for (int r = 0; r < 4; ++r) psum[r] += __shfl_xor(psum[r], off, 64);
#pragma unroll
    for (int r = 0; r < 4; ++r) lrow[r] += psum[r];

    __syncthreads();   // P visible to all lanes; K reads done

    const bf16x8 pa0 = *(const bf16x8*)(pl + l16 * 64 + lg * 8);
    const bf16x8 pa1 = *(const bf16x8*)(pl + l16 * 64 + 32 + lg * 8);
#pragma unroll
    for (int df = 0; df < 4; ++df) {
      const bf16x8 bv0 = *(const bf16x8*)(Vlds + (df * 16 + l16) * HEAD_ + lg * 8);
      const bf16x8 bv1 = *(const bf16x8*)(Vlds + (df * 16 + l16) * HEAD_ + 32 + lg * 8);
      oacc[df] = __builtin_amdgcn_mfma_f32_16x16x32_bf16(pa0, bv0, oacc[df], 0, 0, 0);
      oacc[df] = __builtin_amdgcn_mfma_f32_16x16x32_bf16(pa1, bv1, oacc[df], 0, 0, 0);
    }
    __syncthreads();   // V/P reads done before next staging
  }

#pragma unroll
  for (int r = 0; r < 4; ++r) {
    const float inv = 1.f / lrow[r];
    const int tq = q0 + wave * 16 + lg * 4 + r;
    unsigned short* yp = Y + ((size_t)(b * T_ + tq)) * EMB_ + h * HEAD_;
#pragma unroll
    for (int df = 0; df < 4; ++df)
      yp[df * 16 + l16] = f2bf(oacc[df][r] * inv);
  }
}

// ---------------- launch ----------------

extern "C" void kernel_launch(void* const* d_in, const int* in_sizes, int n_in,
                              void* d_out, int out_size, void* d_ws, size_t ws_size,
                              hipStream_t stream) {
  const float* x  = (const float*)d_in[0];
  const float* Wq = (const float*)d_in[1];
  const float* bq = (const float*)d_in[2];
  const float* Wk = (const float*)d_in[3];
  const float* bk = (const float*)d_in[4];
  const float* Wv = (const float*)d_in[5];
  const float* bv = (const float*)d_in[6];
  const float* Wo = (const float*)d_in[7];
  const float* bo = (const float*)d_in[8];
  float* out = (float*)d_out;

  char* ws = (char*)d_ws;
  size_t off = 0;
  auto alloc = [&](size_t bytes) {
    void* p = ws + off;
    off += (bytes + 255) & ~(size_t)255;
    return p;
  };
  unsigned short* xb     = (unsigned short*)alloc((size_t)M_ * EMB_ * 2);
  unsigned short* WqkvT  = (unsigned short*)alloc((size_t)NTOT_ * EMB_ * 2);
  unsigned short* WoT    = (unsigned short*)alloc((size_t)EMB_ * EMB_ * 2);
  float*          bcat   = (float*)alloc((size_t)NTOT_ * 4);
  float*          QKVlin = (float*)alloc((size_t)M_ * NTOT_ * 4);
  unsigned short* Qh     = (unsigned short*)alloc((size_t)B_ * NQ_ * T_ * HEAD_ * 2);
  unsigned short* Kh     = (unsigned short*)alloc((size_t)B_ * NKV_ * T_ * HEAD_ * 2);
  unsigned short* Vt     = (unsigned short*)alloc((size_t)B_ * NKV_ * HEAD_ * T_ * 2);
  unsigned short* Yb     = (unsigned short*)alloc((size_t)M_ * EMB_ * 2);

  // 1. x -> bf16
  cvt_bf16_kernel<<<(M_ * EMB_ / 4 + 255) / 256, 256, 0, stream>>>(x, xb, M_ * EMB_ / 4);

  // 2. weight transposes (W[K][N] -> WT[N][K] bf16), fused QKV + bias concat
  dim3 tb(32, 8);
  transpose_cvt_kernel<<<dim3(EMB_ / 32, EMB_ / 32), tb, 0, stream>>>(Wq, WqkvT, EMB_, EMB_);
  transpose_cvt_kernel<<<dim3(512 / 32, EMB_ / 32), tb, 0, stream>>>(Wk, WqkvT + (size_t)2048 * 2048, EMB_, 512);
  transpose_cvt_kernel<<<dim3(512 / 32, EMB_ / 32), tb, 0, stream>>>(Wv, WqkvT + (size_t)2560 * 2048, EMB_, 512);
  transpose_cvt_kernel<<<dim3(EMB_ / 32, EMB_ / 32), tb, 0, stream>>>(Wo, WoT, EMB_, EMB_);
  concat_bias_kernel<<<(NTOT_ + 255) / 256, 256, 0, stream>>>(bq, bk, bv, bcat);

  // 3. fused QKV projection: QKVlin[4096][3072] = xb @ WqkvT^T + bcat
  gemm_bt_bias<<<dim3(M_ / 128, NTOT_ / 128), 256, 0, stream>>>(xb, WqkvT, bcat, QKVlin, NTOT_, EMB_);

  // 4. RoPE + head relayout
  rope_q_kernel<<<(B_ * T_ * NQ_ * 32) / 256, 256, 0, stream>>>(QKVlin, Qh);
  rope_k_kernel<<<(B_ * T_ * NKV_ * 32) / 256, 256, 0, stream>>>(QKVlin, Kh);
  vt_kernel<<<(B_ * NKV_ * HEAD_ * T_) / 256, 256, 0, stream>>>(QKVlin, Vt);

  // 5. causal GQA flash attention -> Yb bf16 [b*t][emb]
  flash_attn_kernel<<<dim3(T_ / 64, NQ_, B_), 256, 0, stream>>>(Qh, Kh, Vt, Yb);

  // 6. output projection (fp32 out, + bo)
  gemm_bt_bias<<<dim3(M_ / 128, EMB_ / 128), 256, 0, stream>>>(Yb, WoT, bo, out, EMB_, EMB_);

  (void)in_sizes; (void)n_in; (void)out_size; (void)ws_size;
}

// Round 2
// 394.323 us; speedup vs baseline: 1.1011x; 1.1011x over previous
//
#include <hip/hip_runtime.h>
#include <cstdint>
#include <cstddef>

typedef __attribute__((ext_vector_type(4))) float f32x4;
typedef __attribute__((ext_vector_type(8))) short bf16x8;

#define B_    2
#define T_    2048
#define EMB_  2048
#define NQ_   32
#define NKV_  8
#define HEAD_ 64
#define NTOT_ 3072          // 2048 (Q) + 512 (K) + 512 (V)
#define M_    (B_ * T_)     // 4096
#define QBLK_ 128

__device__ __forceinline__ unsigned short f2bf(float f) {
  union { float f; unsigned int u; } v; v.f = f;
  unsigned int r = v.u + 0x7fffu + ((v.u >> 16) & 1u);
  return (unsigned short)(r >> 16);
}

__device__ __forceinline__ void gload_lds16(const void* g, void* l) {
  __builtin_amdgcn_global_load_lds(
      (const __attribute__((address_space(1))) void*)g,
      (__attribute__((address_space(3))) void*)l, 16, 0, 0);
}

// ---------------- elementwise converts / relayouts ----------------

__global__ void cvt_bf16_kernel(const float* __restrict__ src,
                                unsigned short* __restrict__ dst, int n4) {
  int i = blockIdx.x * blockDim.x + threadIdx.x;
  if (i >= n4) return;
  float4 v = ((const float4*)src)[i];
  unsigned long long pk =
      (unsigned long long)f2bf(v.x) |
      ((unsigned long long)f2bf(v.y) << 16) |
      ((unsigned long long)f2bf(v.z) << 32) |
      ((unsigned long long)f2bf(v.w) << 48);
  *(unsigned long long*)(dst + (size_t)i * 4) = pk;
}

// src fp32 [R][C]  ->  dst bf16 [C][R]
__global__ void transpose_cvt_kernel(const float* __restrict__ src,
                                     unsigned short* __restrict__ dst,
                                     int R, int C) {
  __shared__ float tile[32][33];
  int c0 = blockIdx.x * 32, r0 = blockIdx.y * 32;
  int tx = threadIdx.x, ty = threadIdx.y;
#pragma unroll
  for (int k = 0; k < 4; ++k)
    tile[ty + 8 * k][tx] = src[(size_t)(r0 + ty + 8 * k) * C + c0 + tx];
  __syncthreads();
#pragma unroll
  for (int k = 0; k < 4; ++k)
    dst[(size_t)(c0 + ty + 8 * k) * R + r0 + tx] = f2bf(tile[tx][ty + 8 * k]);
}

__global__ void concat_bias_kernel(const float* __restrict__ bq,
                                   const float* __restrict__ bk,
                                   const float* __restrict__ bv,
                                   float* __restrict__ dst) {
  int i = blockIdx.x * 256 + threadIdx.x;
  if (i < 2048) dst[i] = bq[i];
  else if (i < 2560) dst[i] = bk[i - 2048];
  else if (i < 3072) dst[i] = bv[i - 2560];
}

#define L2_10000 13.2877123795494f

// QKVlin fp32 [4096][3072] -> Qh bf16 [b][h][t][64] with RoPE
__global__ void rope_q_kernel(const float* __restrict__ qkv,
                              unsigned short* __restrict__ Qh) {
  int idx = blockIdx.x * 256 + threadIdx.x;   // B*T*NQ*32
  int i  = idx & 31;
  int h  = (idx >> 5) & 31;
  int bt = idx >> 10;
  int t  = bt & (T_ - 1);
  int b  = bt >> 11;
  float invf = exp2f(-(float)i * (L2_10000 / 32.f));
  float ang = (float)t * invf;
  float s, c; sincosf(ang, &s, &c);
  const float* row = qkv + (size_t)bt * NTOT_ + h * 64;
  float x1 = row[i], x2 = row[i + 32];
  unsigned short* q = Qh + ((size_t)(b * NQ_ + h) * T_ + t) * HEAD_;
  q[i]      = f2bf(x1 * c - x2 * s);
  q[i + 32] = f2bf(x2 * c + x1 * s);
}

__global__ void rope_k_kernel(const float* __restrict__ qkv,
                              unsigned short* __restrict__ Kh) {
  int idx = blockIdx.x * 256 + threadIdx.x;   // B*T*NKV*32
  int i  = idx & 31;
  int kh = (idx >> 5) & 7;
  int bt = idx >> 8;
  int t  = bt & (T_ - 1);
  int b  = bt >> 11;
  float invf = exp2f(-(float)i * (L2_10000 / 32.f));
  float ang = (float)t * invf;
  float s, c; sincosf(ang, &s, &c);
  const float* row = qkv + (size_t)bt * NTOT_ + 2048 + kh * 64;
  float x1 = row[i], x2 = row[i + 32];
  unsigned short* kp = Kh + ((size_t)(b * NKV_ + kh) * T_ + t) * HEAD_;
  kp[i]      = f2bf(x1 * c - x2 * s);
  kp[i + 32] = f2bf(x2 * c + x1 * s);
}

// V -> Vt bf16 [b][kh][d][t]
__global__ void vt_kernel(const float* __restrict__ qkv,
                          unsigned short* __restrict__ Vt) {
  int idx = blockIdx.x * 256 + threadIdx.x;   // B*NKV*HEAD*T
  int t  = idx & (T_ - 1);
  int d  = (idx >> 11) & 63;
  int kh = (idx >> 17) & 7;
  int b  = idx >> 20;
  float v = qkv[(size_t)(b * T_ + t) * NTOT_ + 2560 + kh * 64 + d];
  Vt[((size_t)((b * NKV_ + kh) * 64 + d)) * T_ + t] = f2bf(v);
}

// ---------------- GEMM: C[M][N] = A[M][K](bf16) x BT[N][K](bf16) + bias ----------------
// 128x128 tile, BK=32, 4 waves (2x2), each wave 64x64 via 4x4 16x16x32 MFMA frags.

__launch_bounds__(256, 2)
__global__ void gemm_bt_bias(const unsigned short* __restrict__ A,
                             const unsigned short* __restrict__ BT,
                             const float* __restrict__ bias,
                             float* __restrict__ C, int N, int K) {
  __shared__ unsigned short Alds[128 * 32];
  __shared__ unsigned short Blds[128 * 32];
  const int tid = threadIdx.x;
  const int wave = tid >> 6, lane = tid & 63;
  const int l16 = lane & 15, lg = lane >> 4;
  const int m0 = blockIdx.x * 128;
  const int n0 = blockIdx.y * 128;
  const int wr = wave >> 1, wc = wave & 1;

  f32x4 zero4 = {0.f, 0.f, 0.f, 0.f};
  f32x4 acc[4][4];
#pragma unroll
  for (int i = 0; i < 4; ++i)
#pragma unroll
    for (int j = 0; j < 4; ++j) acc[i][j] = zero4;

  const int arow = tid >> 2;       // 0..63
  const int kcb  = (tid & 3) * 8;  // element offset within BK
  const int nk = K >> 5;
  for (int kt = 0; kt < nk; ++kt) {
    const int k0 = kt << 5;
    gload_lds16(A + (size_t)(m0 + arow) * K + k0 + kcb,       (char*)Alds + tid * 16);
    gload_lds16(A + (size_t)(m0 + 64 + arow) * K + k0 + kcb,  (char*)Alds + 4096 + tid * 16);
    gload_lds16(BT + (size_t)(n0 + arow) * K + k0 + kcb,      (char*)Blds + tid * 16);
    gload_lds16(BT + (size_t)(n0 + 64 + arow) * K + k0 + kcb, (char*)Blds + 4096 + tid * 16);
    __syncthreads();
    bf16x8 af[4], bfr[4];
#pragma unroll
    for (int i = 0; i < 4; ++i)
      af[i] = *(const bf16x8*)(Alds + (wr * 64 + i * 16 + l16) * 32 + lg * 8);
#pragma unroll
    for (int j = 0; j < 4; ++j)
      bfr[j] = *(const bf16x8*)(Blds + (wc * 64 + j * 16 + l16) * 32 + lg * 8);
#pragma unroll
    for (int i = 0; i < 4; ++i)
#pragma unroll
      for (int j = 0; j < 4; ++j)
        acc[i][j] = __builtin_amdgcn_mfma_f32_16x16x32_bf16(af[i], bfr[j], acc[i][j], 0, 0, 0);
    __syncthreads();
  }
#pragma unroll
  for (int j = 0; j < 4; ++j) {
    const int col = n0 + wc * 64 + j * 16 + l16;
    const float bv = bias[col];
#pragma unroll
    for (int i = 0; i < 4; ++i) {
      const int rowb = m0 + wr * 64 + i * 16 + lg * 4;
#pragma unroll
      for (int r = 0; r < 4; ++r)
        C[(size_t)(rowb + r) * N + col] = acc[i][j][r] + bv;
    }
  }
}

// ---------------- flash attention (causal, GQA) ----------------
// grid (T/128, NQ, B); 4 waves x 32 q-rows; KV tiles of 64.
// All LDS tiles XOR-swizzled in 16B units: unit ^= (row & 7).
// K/V staged via global_load_lds with PRE-SWIZZLED global source column
// (linear LDS dest), P reg-staged with swizzled write + read.

__launch_bounds__(256, 3)
__global__ void flash_attn_kernel(const unsigned short* __restrict__ Qh,
                                  const unsigned short* __restrict__ Kh,
                                  const unsigned short* __restrict__ Vt,
                                  unsigned short* __restrict__ Y) {
  __shared__ unsigned short Klds[64 * 64];   // [kv][d] swizzled
  __shared__ unsigned short Vlds[64 * 64];   // [d][kv] swizzled
  __shared__ unsigned short Plds[4][32 * 64];// per-wave [qrow][kv] swizzled
  const int tid = threadIdx.x;
  const int wave = tid >> 6, lane = tid & 63;
  const int l16 = lane & 15, lg = lane >> 4;
  const int qt = gridDim.x - 1 - blockIdx.x;   // heavy blocks first
  const int q0 = qt * QBLK_;
  const int h = blockIdx.y, b = blockIdx.z;
  const int kh = h >> 2;   // N_REP = 4

  // Q fragments: wave handles rows q0 + wave*32 + {0..31}
  bf16x8 aq[2][2];
#pragma unroll
  for (int i = 0; i < 2; ++i) {
    const unsigned short* qp =
        Qh + ((size_t)(b * NQ_ + h) * T_ + q0 + wave * 32 + i * 16 + l16) * HEAD_;
    aq[i][0] = *(const bf16x8*)(qp + lg * 8);
    aq[i][1] = *(const bf16x8*)(qp + 32 + lg * 8);
  }

  f32x4 zero4 = {0.f, 0.f, 0.f, 0.f};
  f32x4 oacc[2][4];
  f32x4 lacc[2];
#pragma unroll
  for (int i = 0; i < 2; ++i) {
    lacc[i] = zero4;
#pragma unroll
    for (int d = 0; d < 4; ++d) oacc[i][d] = zero4;
  }
  float mrow[2][4];
#pragma unroll
  for (int i = 0; i < 2; ++i)
#pragma unroll
    for (int r = 0; r < 4; ++r) mrow[i][r] = -1e30f;

  const short one_bf = (short)0x3F80;
  const bf16x8 onesv = {one_bf, one_bf, one_bf, one_bf,
                        one_bf, one_bf, one_bf, one_bf};

  const size_t kbase = (size_t)(b * NKV_ + kh) * T_ * HEAD_;
  const size_t vbase = (size_t)(b * NKV_ + kh) * HEAD_ * T_;
  const int ntile = (q0 >> 6) + 2;

  // staging geometry: dest byte = (tid + i*256)*16 -> row=(tid>>3)+i*32,
  // 16B unit c = tid&7; swizzled source unit = c ^ (row&7)
  const int srow = tid >> 3;
  const int csrc = (tid & 7) ^ (srow & 7);   // (srow+32)&7 == srow&7

  unsigned short* pl = Plds[wave];

  for (int t = 0; t < ntile; ++t) {
    const int kv0 = t * 64;
    gload_lds16(Kh + kbase + (size_t)(kv0 + srow) * HEAD_ + csrc * 8,
                (char*)Klds + tid * 16);
    gload_lds16(Kh + kbase + (size_t)(kv0 + srow + 32) * HEAD_ + csrc * 8,
                (char*)Klds + (tid + 256) * 16);
    gload_lds16(Vt + vbase + (size_t)srow * T_ + kv0 + csrc * 8,
                (char*)Vlds + tid * 16);
    gload_lds16(Vt + vbase + (size_t)(srow + 32) * T_ + kv0 + csrc * 8,
                (char*)Vlds + (tid + 256) * 16);
    __syncthreads();

    // ---- QK^T -> S[32 q rows][64 kv] per wave ----
    float sv[2][4][4];
    float pm[2][4];
#pragma unroll
    for (int i = 0; i < 2; ++i)
#pragma unroll
      for (int r = 0; r < 4; ++r) pm[i][r] = -1e30f;

    const bool diag = (t >= ntile - 2);
#pragma unroll
    for (int cf = 0; cf < 4; ++cf) {
      const int kr = cf * 16 + l16;
      const bf16x8 bk0 = *(const bf16x8*)(Klds + kr * 64 + ((lg ^ (kr & 7)) << 3));
      const bf16x8 bk1 = *(const bf16x8*)(Klds + kr * 64 + (((4 + lg) ^ (kr & 7)) << 3));
      const int kvg = kv0 + kr;
#pragma unroll
      for (int i = 0; i < 2; ++i) {
        f32x4 z = zero4;
        z = __builtin_amdgcn_mfma_f32_16x16x32_bf16(aq[i][0], bk0, z, 0, 0, 0);
        z = __builtin_amdgcn_mfma_f32_16x16x32_bf16(aq[i][1], bk1, z, 0, 0, 0);
        const int qr0 = q0 + wave * 32 + i * 16 + lg * 4;
#pragma unroll
        for (int r = 0; r < 4; ++r) {
          float s = z[r] * 0.125f;
          if (diag && kvg > qr0 + r) s = -1e30f;
          sv[i][cf][r] = s;
          pm[i][r] = fmaxf(pm[i][r], s);
        }
      }
    }
    // row max across l16 lanes
#pragma unroll
    for (int off = 8; off >= 1; off >>= 1)
#pragma unroll
      for (int i = 0; i < 2; ++i)
#pragma unroll
        for (int r = 0; r < 4; ++r)
          pm[i][r] = fmaxf(pm[i][r], __shfl_xor(pm[i][r], off, 64));

    // online-softmax rescale
#pragma unroll
    for (int i = 0; i < 2; ++i) {
      float corr[4];
#pragma unroll
      for (int r = 0; r < 4; ++r) {
        const float mnew = fmaxf(mrow[i][r], pm[i][r]);
        corr[r] = __expf(mrow[i][r] - mnew);
        mrow[i][r] = mnew;
        lacc[i][r] *= corr[r];
      }
#pragma unroll
      for (int df = 0; df < 4; ++df)
#pragma unroll
        for (int r = 0; r < 4; ++r) oacc[i][df][r] *= corr[r];
    }

    // exp + P -> LDS (swizzled write)
#pragma unroll
    for (int i = 0; i < 2; ++i)
#pragma unroll
      for (int cf = 0; cf < 4; ++cf) {
        const int u = cf * 2 + (l16 >> 3);
#pragma unroll
        for (int r = 0; r < 4; ++r) {
          const int row = i * 16 + lg * 4 + r;
          const float p = __expf(sv[i][cf][r] - mrow[i][r]);
          pl[row * 64 + ((u ^ (row & 7)) << 3) + (l16 & 7)] = f2bf(p);
        }
      }

    // ---- PV + row-sum (ones-MFMA), per-wave private P: no barrier needed ----
#pragma unroll
    for (int i = 0; i < 2; ++i) {
      const int prow = i * 16 + l16;
      const bf16x8 pa0 = *(const bf16x8*)(pl + prow * 64 + ((lg ^ (prow & 7)) << 3));
      const bf16x8 pa1 = *(const bf16x8*)(pl + prow * 64 + (((4 + lg) ^ (prow & 7)) << 3));
      lacc[i] = __builtin_amdgcn_mfma_f32_16x16x32_bf16(pa0, onesv, lacc[i], 0, 0, 0);
      lacc[i] = __builtin_amdgcn_mfma_f32_16x16x32_bf16(pa1, onesv, lacc[i], 0, 0, 0);
#pragma unroll
      for (int df = 0; df < 4; ++df) {
        const int vr = df * 16 + l16;
        const bf16x8 bv0 = *(const bf16x8*)(Vlds + vr * 64 + ((lg ^ (vr & 7)) << 3));
        const bf16x8 bv1 = *(const bf16x8*)(Vlds + vr * 64 + (((4 + lg) ^ (vr & 7)) << 3));
        oacc[i][df] = __builtin_amdgcn_mfma_f32_16x16x32_bf16(pa0, bv0, oacc[i][df], 0, 0, 0);
        oacc[i][df] = __builtin_amdgcn_mfma_f32_16x16x32_bf16(pa1, bv1, oacc[i][df], 0, 0, 0);
      }
    }
    __syncthreads();   // K/V reads done before next staging
  }

#pragma unroll
  for (int i = 0; i < 2; ++i)
#pragma unroll
    for (int r = 0; r < 4; ++r) {
      const float inv = 1.f / lacc[i][r];
      const int tq = q0 + wave * 32 + i * 16 + lg * 4 + r;
      unsigned short* yp = Y + ((size_t)(b * T_ + tq)) * EMB_ + h * HEAD_;
#pragma unroll
      for (int df = 0; df < 4; ++df)
        yp[df * 16 + l16] = f2bf(oacc[i][df][r] * inv);
    }
}

// ---------------- launch ----------------

extern "C" void kernel_launch(void* const* d_in, const int* in_sizes, int n_in,
                              void* d_out, int out_size, void* d_ws, size_t ws_size,
                              hipStream_t stream) {
  const float* x  = (const float*)d_in[0];
  const float* Wq = (const float*)d_in[1];
  const float* bq = (const float*)d_in[2];
  const float* Wk = (const float*)d_in[3];
  const float* bk = (const float*)d_in[4];
  const float* Wv = (const float*)d_in[5];
  const float* bv = (const float*)d_in[6];
  const float* Wo = (const float*)d_in[7];
  const float* bo = (const float*)d_in[8];
  float* out = (float*)d_out;

  char* ws = (char*)d_ws;
  size_t off = 0;
  auto alloc = [&](size_t bytes) {
    void* p = ws + off;
    off += (bytes + 255) & ~(size_t)255;
    return p;
  };
  unsigned short* xb     = (unsigned short*)alloc((size_t)M_ * EMB_ * 2);
  unsigned short* WqkvT  = (unsigned short*)alloc((size_t)NTOT_ * EMB_ * 2);
  unsigned short* WoT    = (unsigned short*)alloc((size_t)EMB_ * EMB_ * 2);
  float*          bcat   = (float*)alloc((size_t)NTOT_ * 4);
  float*          QKVlin = (float*)alloc((size_t)M_ * NTOT_ * 4);
  unsigned short* Qh     = (unsigned short*)alloc((size_t)B_ * NQ_ * T_ * HEAD_ * 2);
  unsigned short* Kh     = (unsigned short*)alloc((size_t)B_ * NKV_ * T_ * HEAD_ * 2);
  unsigned short* Vt     = (unsigned short*)alloc((size_t)B_ * NKV_ * HEAD_ * T_ * 2);
  unsigned short* Yb     = (unsigned short*)alloc((size_t)M_ * EMB_ * 2);

  // 1. x -> bf16
  cvt_bf16_kernel<<<(M_ * EMB_ / 4 + 255) / 256, 256, 0, stream>>>(x, xb, M_ * EMB_ / 4);

  // 2. weight transposes (W[K][N] -> WT[N][K] bf16), fused QKV + bias concat
  dim3 tb(32, 8);
  transpose_cvt_kernel<<<dim3(EMB_ / 32, EMB_ / 32), tb, 0, stream>>>(Wq, WqkvT, EMB_, EMB_);
  transpose_cvt_kernel<<<dim3(512 / 32, EMB_ / 32), tb, 0, stream>>>(Wk, WqkvT + (size_t)2048 * 2048, EMB_, 512);
  transpose_cvt_kernel<<<dim3(512 / 32, EMB_ / 32), tb, 0, stream>>>(Wv, WqkvT + (size_t)2560 * 2048, EMB_, 512);
  transpose_cvt_kernel<<<dim3(EMB_ / 32, EMB_ / 32), tb, 0, stream>>>(Wo, WoT, EMB_, EMB_);
  concat_bias_kernel<<<(NTOT_ + 255) / 256, 256, 0, stream>>>(bq, bk, bv, bcat);

  // 3. fused QKV projection: QKVlin[4096][3072] = xb @ WqkvT^T + bcat
  gemm_bt_bias<<<dim3(M_ / 128, NTOT_ / 128), 256, 0, stream>>>(xb, WqkvT, bcat, QKVlin, NTOT_, EMB_);

  // 4. RoPE + head relayout
  rope_q_kernel<<<(B_ * T_ * NQ_ * 32) / 256, 256, 0, stream>>>(QKVlin, Qh);
  rope_k_kernel<<<(B_ * T_ * NKV_ * 32) / 256, 256, 0, stream>>>(QKVlin, Kh);
  vt_kernel<<<(B_ * NKV_ * HEAD_ * T_) / 256, 256, 0, stream>>>(QKVlin, Vt);

  // 5. causal GQA flash attention -> Yb bf16 [b*t][emb]
  flash_attn_kernel<<<dim3(T_ / QBLK_, NQ_, B_), 256, 0, stream>>>(Qh, Kh, Vt, Yb);

  // 6. output projection (fp32 out, + bo)
  gemm_bt_bias<<<dim3(M_ / 128, EMB_ / 128), 256, 0, stream>>>(Yb, WoT, bo, out, EMB_, EMB_);

  (void)in_sizes; (void)n_in; (void)out_size; (void)ws_size;
}

// Round 3
// 237.742 us; speedup vs baseline: 1.8262x; 1.6586x over previous
//
#include <hip/hip_runtime.h>
#include <hip/hip_bf16.h>
#include <cstdint>
#include <cstddef>

typedef __attribute__((ext_vector_type(4))) float f32x4;
typedef __attribute__((ext_vector_type(8))) short bf16x8;

#define B_    2
#define T_    2048
#define EMB_  2048
#define NQ_   32
#define NKV_  8
#define HEAD_ 64
#define NTOT_ 3072          // 2048 (Q) + 512 (K) + 512 (V)
#define M_    (B_ * T_)     // 4096
#define QBLK_ 128

__device__ __forceinline__ unsigned short f2bf(float f) {
  union { float f; unsigned int u; } v; v.f = f;
  unsigned int r = v.u + 0x7fffu + ((v.u >> 16) & 1u);
  return (unsigned short)(r >> 16);
}

__device__ __forceinline__ unsigned int pk_bf16(float lo, float hi) {
  __hip_bfloat162 h = __float22bfloat162_rn(make_float2(lo, hi));
  union { __hip_bfloat162 h; unsigned int u; } c; c.h = h;
  return c.u;
}

__device__ __forceinline__ void gload_lds16(const void* g, void* l) {
  __builtin_amdgcn_global_load_lds(
      (const __attribute__((address_space(1))) void*)g,
      (__attribute__((address_space(3))) void*)l, 16, 0, 0);
}

// ---------------- elementwise converts / relayouts ----------------

__global__ void cvt_bf16_kernel(const float* __restrict__ src,
                                unsigned short* __restrict__ dst, int n4) {
  int i = blockIdx.x * blockDim.x + threadIdx.x;
  if (i >= n4) return;
  float4 v = ((const float4*)src)[i];
  unsigned long long pk =
      (unsigned long long)f2bf(v.x) |
      ((unsigned long long)f2bf(v.y) << 16) |
      ((unsigned long long)f2bf(v.z) << 32) |
      ((unsigned long long)f2bf(v.w) << 48);
  *(unsigned long long*)(dst + (size_t)i * 4) = pk;
}

// src fp32 [R][C]  ->  dst bf16 [C][R]
__global__ void transpose_cvt_kernel(const float* __restrict__ src,
                                     unsigned short* __restrict__ dst,
                                     int R, int C) {
  __shared__ float tile[32][33];
  int c0 = blockIdx.x * 32, r0 = blockIdx.y * 32;
  int tx = threadIdx.x, ty = threadIdx.y;
#pragma unroll
  for (int k = 0; k < 4; ++k)
    tile[ty + 8 * k][tx] = src[(size_t)(r0 + ty + 8 * k) * C + c0 + tx];
  __syncthreads();
#pragma unroll
  for (int k = 0; k < 4; ++k)
    dst[(size_t)(c0 + ty + 8 * k) * R + r0 + tx] = f2bf(tile[tx][ty + 8 * k]);
}

__global__ void concat_bias_kernel(const float* __restrict__ bq,
                                   const float* __restrict__ bk,
                                   const float* __restrict__ bv,
                                   float* __restrict__ dst) {
  int i = blockIdx.x * 256 + threadIdx.x;
  if (i < 2048) dst[i] = bq[i];
  else if (i < 2560) dst[i] = bk[i - 2048];
  else if (i < 3072) dst[i] = bv[i - 2560];
}

#define L2_10000 13.2877123795494f

// QKVlin fp32 [4096][3072] -> Qh bf16 [b][h][t][64] with RoPE.
// Softmax scale 1/sqrt(64)=0.125 folded in here (free).
__global__ void rope_q_kernel(const float* __restrict__ qkv,
                              unsigned short* __restrict__ Qh) {
  int idx = blockIdx.x * 256 + threadIdx.x;   // B*T*NQ*32
  int i  = idx & 31;
  int h  = (idx >> 5) & 31;
  int bt = idx >> 10;
  int t  = bt & (T_ - 1);
  int b  = bt >> 11;
  float invf = exp2f(-(float)i * (L2_10000 / 32.f));
  float ang = (float)t * invf;
  float s, c; sincosf(ang, &s, &c);
  const float* row = qkv + (size_t)bt * NTOT_ + h * 64;
  float x1 = row[i], x2 = row[i + 32];
  unsigned short* q = Qh + ((size_t)(b * NQ_ + h) * T_ + t) * HEAD_;
  q[i]      = f2bf((x1 * c - x2 * s) * 0.125f);
  q[i + 32] = f2bf((x2 * c + x1 * s) * 0.125f);
}

__global__ void rope_k_kernel(const float* __restrict__ qkv,
                              unsigned short* __restrict__ Kh) {
  int idx = blockIdx.x * 256 + threadIdx.x;   // B*T*NKV*32
  int i  = idx & 31;
  int kh = (idx >> 5) & 7;
  int bt = idx >> 8;
  int t  = bt & (T_ - 1);
  int b  = bt >> 11;
  float invf = exp2f(-(float)i * (L2_10000 / 32.f));
  float ang = (float)t * invf;
  float s, c; sincosf(ang, &s, &c);
  const float* row = qkv + (size_t)bt * NTOT_ + 2048 + kh * 64;
  float x1 = row[i], x2 = row[i + 32];
  unsigned short* kp = Kh + ((size_t)(b * NKV_ + kh) * T_ + t) * HEAD_;
  kp[i]      = f2bf(x1 * c - x2 * s);
  kp[i + 32] = f2bf(x2 * c + x1 * s);
}

// V -> Vt bf16 [b][kh][d][t]
__global__ void vt_kernel(const float* __restrict__ qkv,
                          unsigned short* __restrict__ Vt) {
  int idx = blockIdx.x * 256 + threadIdx.x;   // B*NKV*HEAD*T
  int t  = idx & (T_ - 1);
  int d  = (idx >> 11) & 63;
  int kh = (idx >> 17) & 7;
  int b  = idx >> 20;
  float v = qkv[(size_t)(b * T_ + t) * NTOT_ + 2560 + kh * 64 + d];
  Vt[((size_t)((b * NKV_ + kh) * 64 + d)) * T_ + t] = f2bf(v);
}

// ---------------- GEMM: C[M][N] = A[M][K](bf16) x BT[N][K](bf16) + bias ----------------

__launch_bounds__(256, 2)
__global__ void gemm_bt_bias(const unsigned short* __restrict__ A,
                             const unsigned short* __restrict__ BT,
                             const float* __restrict__ bias,
                             float* __restrict__ C, int N, int K) {
  __shared__ unsigned short Alds[128 * 32];
  __shared__ unsigned short Blds[128 * 32];
  const int tid = threadIdx.x;
  const int wave = tid >> 6, lane = tid & 63;
  const int l16 = lane & 15, lg = lane >> 4;
  const int m0 = blockIdx.x * 128;
  const int n0 = blockIdx.y * 128;
  const int wr = wave >> 1, wc = wave & 1;

  f32x4 zero4 = {0.f, 0.f, 0.f, 0.f};
  f32x4 acc[4][4];
#pragma unroll
  for (int i = 0; i < 4; ++i)
#pragma unroll
    for (int j = 0; j < 4; ++j) acc[i][j] = zero4;

  const int arow = tid >> 2;
  const int kcb  = (tid & 3) * 8;
  const int nk = K >> 5;
  for (int kt = 0; kt < nk; ++kt) {
    const int k0 = kt << 5;
    gload_lds16(A + (size_t)(m0 + arow) * K + k0 + kcb,       (char*)Alds + tid * 16);
    gload_lds16(A + (size_t)(m0 + 64 + arow) * K + k0 + kcb,  (char*)Alds + 4096 + tid * 16);
    gload_lds16(BT + (size_t)(n0 + arow) * K + k0 + kcb,      (char*)Blds + tid * 16);
    gload_lds16(BT + (size_t)(n0 + 64 + arow) * K + k0 + kcb, (char*)Blds + 4096 + tid * 16);
    __syncthreads();
    bf16x8 af[4], bfr[4];
#pragma unroll
    for (int i = 0; i < 4; ++i)
      af[i] = *(const bf16x8*)(Alds + (wr * 64 + i * 16 + l16) * 32 + lg * 8);
#pragma unroll
    for (int j = 0; j < 4; ++j)
      bfr[j] = *(const bf16x8*)(Blds + (wc * 64 + j * 16 + l16) * 32 + lg * 8);
#pragma unroll
    for (int i = 0; i < 4; ++i)
#pragma unroll
      for (int j = 0; j < 4; ++j)
        acc[i][j] = __builtin_amdgcn_mfma_f32_16x16x32_bf16(af[i], bfr[j], acc[i][j], 0, 0, 0);
    __syncthreads();
  }
#pragma unroll
  for (int j = 0; j < 4; ++j) {
    const int col = n0 + wc * 64 + j * 16 + l16;
    const float bv = bias[col];
#pragma unroll
    for (int i = 0; i < 4; ++i) {
      const int rowb = m0 + wr * 64 + i * 16 + lg * 4;
#pragma unroll
      for (int r = 0; r < 4; ++r)
        C[(size_t)(rowb + r) * N + col] = acc[i][j][r] + bv;
    }
  }
}

// ---------------- flash attention (causal, GQA), swapped-QK^T ----------------
// grid (8, NQ, B); block handles q-tiles x and 15-x (34 KV-tiles, balanced).
// 4 waves x 32 q rows. S^T via mfma(K,Q): lane owns q=l16, kv=cf*16+lg*4+r.
// PV via mfma(V^T,P): output O^T, d in-lane. K/V double-buffered, counted vmcnt.

__launch_bounds__(256, 2)
__global__ void flash_attn_kernel(const unsigned short* __restrict__ Qh,
                                  const unsigned short* __restrict__ Kh,
                                  const unsigned short* __restrict__ Vt,
                                  unsigned short* __restrict__ Y) {
  __shared__ unsigned short Klds[2][64 * 64];   // [kv][d], 16B-unit swizzled
  __shared__ unsigned short Vlds[2][64 * 64];   // [d][kv], 16B-unit swizzled
  __shared__ unsigned short Plds[4][32 * 64];   // per-wave [q][kv], swizzled
  const int tid = threadIdx.x;
  const int wave = tid >> 6, lane = tid & 63;
  const int l16 = lane & 15, lg = lane >> 4;
  const int h = blockIdx.y, b = blockIdx.z;
  const int kh = h >> 2;   // N_REP = 4

  const size_t kbase = (size_t)(b * NKV_ + kh) * T_ * HEAD_;
  const size_t vbase = (size_t)(b * NKV_ + kh) * HEAD_ * T_;
  const int srow = tid >> 3;
  const int csrc = (tid & 7) ^ (srow & 7);
  unsigned short* pl = Plds[wave];
  const f32x4 zero4 = {0.f, 0.f, 0.f, 0.f};

#define STAGE(bi, kv0) do {                                                         \
    gload_lds16(Kh + kbase + (size_t)((kv0) + srow) * HEAD_ + csrc * 8,             \
                (char*)Klds[bi] + tid * 16);                                        \
    gload_lds16(Kh + kbase + (size_t)((kv0) + srow + 32) * HEAD_ + csrc * 8,        \
                (char*)Klds[bi] + 4096 + tid * 16);                                 \
    gload_lds16(Vt + vbase + (size_t)srow * T_ + (kv0) + csrc * 8,                  \
                (char*)Vlds[bi] + tid * 16);                                        \
    gload_lds16(Vt + vbase + (size_t)(srow + 32) * T_ + (kv0) + csrc * 8,           \
                (char*)Vlds[bi] + 4096 + tid * 16);                                 \
  } while (0)

  for (int seg = 0; seg < 2; ++seg) {
    const int qt = seg ? (15 - (int)blockIdx.x) : (int)blockIdx.x;
    const int q0 = qt * QBLK_;
    const int nt = (q0 >> 6) + 2;

    // Q fragments (B-operand): lane holds Q[q=q0+wave*32+qh*16+l16][d=kd*32+lg*8..]
    bf16x8 aq[2][2];
#pragma unroll
    for (int qh = 0; qh < 2; ++qh) {
      const unsigned short* qp =
          Qh + ((size_t)(b * NQ_ + h) * T_ + q0 + wave * 32 + qh * 16 + l16) * HEAD_;
      aq[qh][0] = *(const bf16x8*)(qp + lg * 8);
      aq[qh][1] = *(const bf16x8*)(qp + 32 + lg * 8);
    }

    f32x4 oacc[2][4];   // O^T[d=df*16+lg*4+r][q=qh*16+l16]
#pragma unroll
    for (int qh = 0; qh < 2; ++qh)
#pragma unroll
      for (int df = 0; df < 4; ++df) oacc[qh][df] = zero4;
    float mreg[2] = {-1e30f, -1e30f};
    float lp[2] = {0.f, 0.f};   // per-lane partial row-sum (own kv slots only)

    STAGE(0, 0);

    for (int t = 0; t < nt; ++t) {
      if (t + 1 < nt) {
        STAGE((t + 1) & 1, (t + 1) * 64);
        asm volatile("s_waitcnt vmcnt(4)" ::: "memory");
      } else {
        asm volatile("s_waitcnt vmcnt(0)" ::: "memory");
      }
      __builtin_amdgcn_s_barrier();
      __builtin_amdgcn_sched_barrier(0);

      const unsigned short* Kb = Klds[t & 1];
      const unsigned short* Vb = Vlds[t & 1];
      const int kv0 = t * 64;

      // ---- S^T = K Q^T : lane holds S[kv=kv0+cf*16+lg*4+r][q] ----
      float p[2][4][4];
#pragma unroll
      for (int cf = 0; cf < 4; ++cf) {
        const int krow = cf * 16 + l16;
        const bf16x8 k0 = *(const bf16x8*)(Kb + krow * 64 + ((lg ^ (krow & 7)) << 3));
        const bf16x8 k1 = *(const bf16x8*)(Kb + krow * 64 + (((4 + lg) ^ (krow & 7)) << 3));
#pragma unroll
        for (int qh = 0; qh < 2; ++qh) {
          f32x4 z = zero4;
          z = __builtin_amdgcn_mfma_f32_16x16x32_bf16(k0, aq[qh][0], z, 0, 0, 0);
          z = __builtin_amdgcn_mfma_f32_16x16x32_bf16(k1, aq[qh][1], z, 0, 0, 0);
#pragma unroll
          for (int r = 0; r < 4; ++r) p[qh][cf][r] = z[r];
        }
      }

      // causal mask only on the two diagonal tiles
      if (t >= nt - 2) {
#pragma unroll
        for (int qh = 0; qh < 2; ++qh) {
          const int qg = q0 + wave * 32 + qh * 16 + l16;
#pragma unroll
          for (int cf = 0; cf < 4; ++cf)
#pragma unroll
            for (int r = 0; r < 4; ++r)
              if (kv0 + cf * 16 + lg * 4 + r > qg) p[qh][cf][r] = -1e30f;
        }
      }

      // ---- online softmax (per-lane column q) ----
#pragma unroll
      for (int qh = 0; qh < 2; ++qh) {
        float pm = p[qh][0][0];
#pragma unroll
        for (int cf = 0; cf < 4; ++cf)
#pragma unroll
          for (int r = 0; r < 4; ++r) pm = fmaxf(pm, p[qh][cf][r]);
        pm = fmaxf(pm, __shfl_xor(pm, 16, 64));
        pm = fmaxf(pm, __shfl_xor(pm, 32, 64));
        const float mnew = fmaxf(mreg[qh], pm);
        const float corr = __expf(mreg[qh] - mnew);
        mreg[qh] = mnew;
        lp[qh] *= corr;
#pragma unroll
        for (int df = 0; df < 4; ++df)
#pragma unroll
          for (int r = 0; r < 4; ++r) oacc[qh][df][r] *= corr;
        float ps = 0.f;
#pragma unroll
        for (int cf = 0; cf < 4; ++cf)
#pragma unroll
          for (int r = 0; r < 4; ++r) {
            const float e = __expf(p[qh][cf][r] - mnew);
            p[qh][cf][r] = e;
            ps += e;
          }
        lp[qh] += ps;
      }

      // ---- P -> LDS (b64 writes, contiguous kv quads), then B-frag reads ----
#pragma unroll
      for (int qh = 0; qh < 2; ++qh) {
        const int row = qh * 16 + l16;
#pragma unroll
        for (int cf = 0; cf < 4; ++cf) {
          const unsigned int w0 = pk_bf16(p[qh][cf][0], p[qh][cf][1]);
          const unsigned int w1 = pk_bf16(p[qh][cf][2], p[qh][cf][3]);
          const int u = cf * 2 + (lg >> 1);
          char* ad = (char*)pl + row * 128 + ((u ^ (row & 7)) << 4) + ((lg & 1) << 3);
          *(unsigned long long*)ad =
              (unsigned long long)w0 | ((unsigned long long)w1 << 32);
        }
      }
      bf16x8 pf[2][2];
#pragma unroll
      for (int qh = 0; qh < 2; ++qh) {
        const int row = qh * 16 + l16;
#pragma unroll
        for (int k2 = 0; k2 < 2; ++k2) {
          const int u = k2 * 4 + lg;
          pf[qh][k2] = *(const bf16x8*)((char*)pl + row * 128 + ((u ^ (row & 7)) << 4));
        }
      }

      // ---- O^T += V^T P^T : A=V^T rows d, B=P rows q ----
#pragma unroll
      for (int df = 0; df < 4; ++df) {
        const int vrow = df * 16 + l16;
        const bf16x8 v0 = *(const bf16x8*)(Vb + vrow * 64 + ((lg ^ (vrow & 7)) << 3));
        const bf16x8 v1 = *(const bf16x8*)(Vb + vrow * 64 + (((4 + lg) ^ (vrow & 7)) << 3));
#pragma unroll
        for (int qh = 0; qh < 2; ++qh) {
          oacc[qh][df] = __builtin_amdgcn_mfma_f32_16x16x32_bf16(v0, pf[qh][0], oacc[qh][df], 0, 0, 0);
          oacc[qh][df] = __builtin_amdgcn_mfma_f32_16x16x32_bf16(v1, pf[qh][1], oacc[qh][df], 0, 0, 0);
        }
      }

      asm volatile("s_waitcnt lgkmcnt(0)" ::: "memory");
      __builtin_amdgcn_sched_barrier(0);
      __builtin_amdgcn_s_barrier();
    }

    // ---- epilogue: reduce l across lane groups, normalize, packed stores ----
#pragma unroll
    for (int qh = 0; qh < 2; ++qh) {
      float lt = lp[qh];
      lt += __shfl_xor(lt, 16, 64);
      lt += __shfl_xor(lt, 32, 64);
      const float inv = 1.f / lt;
      const int tq = q0 + wave * 32 + qh * 16 + l16;
      unsigned short* yp = Y + ((size_t)(b * T_ + tq)) * EMB_ + h * HEAD_;
#pragma unroll
      for (int df = 0; df < 4; ++df) {
        const unsigned int w0 = pk_bf16(oacc[qh][df][0] * inv, oacc[qh][df][1] * inv);
        const unsigned int w1 = pk_bf16(oacc[qh][df][2] * inv, oacc[qh][df][3] * inv);
        *(unsigned long long*)(yp + df * 16 + lg * 4) =
            (unsigned long long)w0 | ((unsigned long long)w1 << 32);
      }
    }
  }
#undef STAGE
}

// ---------------- launch ----------------

extern "C" void kernel_launch(void* const* d_in, const int* in_sizes, int n_in,
                              void* d_out, int out_size, void* d_ws, size_t ws_size,
                              hipStream_t stream) {
  const float* x  = (const float*)d_in[0];
  const float* Wq = (const float*)d_in[1];
  const float* bq = (const float*)d_in[2];
  const float* Wk = (const float*)d_in[3];
  const float* bk = (const float*)d_in[4];
  const float* Wv = (const float*)d_in[5];
  const float* bv = (const float*)d_in[6];
  const float* Wo = (const float*)d_in[7];
  const float* bo = (const float*)d_in[8];
  float* out = (float*)d_out;

  char* ws = (char*)d_ws;
  size_t off = 0;
  auto alloc = [&](size_t bytes) {
    void* p = ws + off;
    off += (bytes + 255) & ~(size_t)255;
    return p;
  };
  unsigned short* xb     = (unsigned short*)alloc((size_t)M_ * EMB_ * 2);
  unsigned short* WqkvT  = (unsigned short*)alloc((size_t)NTOT_ * EMB_ * 2);
  unsigned short* WoT    = (unsigned short*)alloc((size_t)EMB_ * EMB_ * 2);
  float*          bcat   = (float*)alloc((size_t)NTOT_ * 4);
  float*          QKVlin = (float*)alloc((size_t)M_ * NTOT_ * 4);
  unsigned short* Qh     = (unsigned short*)alloc((size_t)B_ * NQ_ * T_ * HEAD_ * 2);
  unsigned short* Kh     = (unsigned short*)alloc((size_t)B_ * NKV_ * T_ * HEAD_ * 2);
  unsigned short* Vt     = (unsigned short*)alloc((size_t)B_ * NKV_ * HEAD_ * T_ * 2);
  unsigned short* Yb     = (unsigned short*)alloc((size_t)M_ * EMB_ * 2);

  cvt_bf16_kernel<<<(M_ * EMB_ / 4 + 255) / 256, 256, 0, stream>>>(x, xb, M_ * EMB_ / 4);

  dim3 tb(32, 8);
  transpose_cvt_kernel<<<dim3(EMB_ / 32, EMB_ / 32), tb, 0, stream>>>(Wq, WqkvT, EMB_, EMB_);
  transpose_cvt_kernel<<<dim3(512 / 32, EMB_ / 32), tb, 0, stream>>>(Wk, WqkvT + (size_t)2048 * 2048, EMB_, 512);
  transpose_cvt_kernel<<<dim3(512 / 32, EMB_ / 32), tb, 0, stream>>>(Wv, WqkvT + (size_t)2560 * 2048, EMB_, 512);
  transpose_cvt_kernel<<<dim3(EMB_ / 32, EMB_ / 32), tb, 0, stream>>>(Wo, WoT, EMB_, EMB_);
  concat_bias_kernel<<<(NTOT_ + 255) / 256, 256, 0, stream>>>(bq, bk, bv, bcat);

  gemm_bt_bias<<<dim3(M_ / 128, NTOT_ / 128), 256, 0, stream>>>(xb, WqkvT, bcat, QKVlin, NTOT_, EMB_);

  rope_q_kernel<<<(B_ * T_ * NQ_ * 32) / 256, 256, 0, stream>>>(QKVlin, Qh);
  rope_k_kernel<<<(B_ * T_ * NKV_ * 32) / 256, 256, 0, stream>>>(QKVlin, Kh);
  vt_kernel<<<(B_ * NKV_ * HEAD_ * T_) / 256, 256, 0, stream>>>(QKVlin, Vt);

  flash_attn_kernel<<<dim3(8, NQ_, B_), 256, 0, stream>>>(Qh, Kh, Vt, Yb);

  gemm_bt_bias<<<dim3(M_ / 128, EMB_ / 128), 256, 0, stream>>>(Yb, WoT, bo, out, EMB_, EMB_);

  (void)in_sizes; (void)n_in; (void)out_size; (void)ws_size;
}